// Round 11
// baseline (144.591 us; speedup 1.0000x reference)
//
#include <hip/hip_runtime.h>
#include <hip/hip_bf16.h>

#define NB 2048      // batch
#define FEAT 2048
#define NBINS 9
#define NATTR 12
#define NPT 20
#define DD 64
#define HH 256
#define QST 264      // shQb row stride (shorts): 132 words == 4 mod 32, rows 16B-aligned
#define ZROW (144 * 72)   // packed Plds: shared zero row offset (shorts)

typedef __attribute__((ext_vector_type(8))) short bf8v;    // 8 bf16 (4 VGPRs) MFMA A/B frag
typedef __attribute__((ext_vector_type(4))) float f4v;     // 16x16 C/D frag
typedef __attribute__((ext_vector_type(16))) float f16v;   // 32x32 C/D frag

__device__ __forceinline__ unsigned short f2bf(float f) {
  unsigned int u = __float_as_uint(f);
  u += 0x7FFFu + ((u >> 16) & 1u);   // round-to-nearest-even
  return (unsigned short)(u >> 16);
}

// packed f32x2 -> bf16x2 (RNE — bit-identical to f2bf)
__device__ __forceinline__ unsigned int pkbf(float x, float y) {
  __hip_bfloat162 h = __float22bfloat162_rn(make_float2(x, y));
  union { __hip_bfloat162 h; unsigned int u; } cv;
  cv.h = h;
  return cv.u;
}

// ---------------------------------------------------------------- K0: merged weight prep
// bid<168: NIMA WT; [168,172): GRU WTg; [172,174): II W1T (K=64);
// [174,302): II W2T; [302,494): node W2Tn
__global__ void k_prep_all(
    const float* __restrict__ Wl, const float* __restrict__ Wa,
    const float* __restrict__ Wih_i, const float* __restrict__ Whh_i,
    const float* __restrict__ Wih_u, const float* __restrict__ Whh_u,
    const float* __restrict__ W1i, const float* __restrict__ W1u,
    const float* __restrict__ W2i, const float* __restrict__ W2u,
    const float* __restrict__ nW2i, const float* __restrict__ nW2u,
    float* __restrict__ WT, unsigned short* __restrict__ WTg,
    unsigned short* __restrict__ W1T, unsigned short* __restrict__ W2T,
    unsigned short* __restrict__ W2Tn) {
  int bid = blockIdx.x, tid = threadIdx.x;
  if (bid < 168) {
    int idx = bid * 256 + tid;
    if (idx < 21 * FEAT) {
      int c = idx / FEAT, k = idx - c * FEAT;
      WT[idx] = (c < NBINS) ? Wl[k * NBINS + c] : Wa[k * NATTR + (c - NBINS)];
    }
  } else if (bid < 172) {
    if (tid < 192) {
      int idx = bid - 168;
      const float* W = idx == 0 ? Wih_i : idx == 1 ? Whh_i : idx == 2 ? Wih_u : Whh_u;
      unsigned short* dst = WTg + (size_t)idx * 192 * 72 + (size_t)tid * 72;
      for (int k = 0; k < DD; ++k) dst[k] = f2bf(W[k * 192 + tid]);
    }
  } else if (bid < 174) {
    int dt = bid - 172;
    const float* W1 = dt ? W1u : W1i;
    unsigned short* dst = W1T + (size_t)dt * (HH * DD) + (size_t)tid * DD;
    for (int k = 0; k < DD; ++k) dst[k] = f2bf(W1[k * HH + tid]);
  } else if (bid < 302) {
    int t = (bid - 174) * 256 + tid;   // 0..32767
    int dt = t >> 14, rem = t & 16383;
    int dp = rem >> 8, k = rem & 255;
    W2T[t] = f2bf((dt ? W2u : W2i)[k * DD + dp]);
  } else {
    int idx8 = (bid - 302) * 256 + tid;   // 0..49151, 8 shorts each
    int dt = idx8 >= 24576;
    int rem = idx8 - dt * 24576;
    int o = rem >> 5, kb = (rem & 31) * 8;
    const float* W2n = dt ? nW2u : nW2i;   // [256][768]
    unsigned short* dst = W2Tn + (size_t)idx8 * 8;
#pragma unroll
    for (int e = 0; e < 8; ++e) dst[e] = f2bf(W2n[(size_t)(kb + e) * 768 + o]);
  }
}

// ---------------------------------------------------------------- K1: NIMA heads + direct path; writes out base
__global__ __launch_bounds__(256) void k_nima(
    const float* __restrict__ A, const float* __restrict__ WT,
    const float* __restrict__ bl, const float* __restrict__ ba,
    const float* __restrict__ dW1, const float* __restrict__ db1,
    const float* __restrict__ dW2, const float* __restrict__ db2,
    const float* __restrict__ corr_b,
    float* __restrict__ attr_raw, float* __restrict__ out) {
  int wave = threadIdx.x >> 6, lane = threadIdx.x & 63;
  int row = blockIdx.x * 4 + wave;
  const float4* A4 = (const float4*)(A + (size_t)row * FEAT);
  float acc[21];
#pragma unroll
  for (int c = 0; c < 21; ++c) acc[c] = 0.f;
#pragma unroll
  for (int it = 0; it < 8; ++it) {
    int kk = it * 64 + lane;
    float4 a = A4[kk];
#pragma unroll
    for (int c = 0; c < 21; ++c) {
      float4 w = ((const float4*)(WT + c * FEAT))[kk];
      acc[c] += a.x * w.x + a.y * w.y + a.z * w.z + a.w * w.w;
    }
  }
#pragma unroll
  for (int c = 0; c < 21; ++c) {
#pragma unroll
    for (int m = 1; m < 64; m <<= 1) acc[c] += __shfl_xor(acc[c], m);
  }
  if (lane == 0) {
#pragma unroll
    for (int c = 0; c < NATTR; ++c) attr_raw[row * NATTR + c] = acc[NBINS + c] + ba[c];
  }
  float l[NBINS];
  float mx = -1e30f;
#pragma unroll
  for (int i = 0; i < NBINS; ++i) { l[i] = acc[i] + bl[i]; mx = fmaxf(mx, l[i]); }
  float s = 0.f;
#pragma unroll
  for (int i = 0; i < NBINS; ++i) { l[i] = __expf(l[i] - mx); s += l[i]; }
  float inv = 1.f / s;
#pragma unroll
  for (int i = 0; i < NBINS; ++i) l[i] *= inv * (1.f + 0.5f * (float)i);
  float partial = 0.f;
#pragma unroll
  for (int hh = 0; hh < 4; ++hh) {
    int h = lane + hh * 64;
    float v = db1[h];
#pragma unroll
    for (int i = 0; i < NBINS; ++i) v += l[i] * dW1[i * HH + h];
    partial += fmaxf(v, 0.f) * dW2[h];
  }
#pragma unroll
  for (int m2 = 1; m2 < 64; m2 <<= 1) partial += __shfl_xor(partial, m2);
  // out base = direct + corr_b; k_gru atomically accumulates the interaction term.
  if (lane == 0) out[row] = partial + db2[0] + corr_b[0];
}

// ---------------------------------------------------------------- K3: node MLPs, layer2 via MFMA
template <int DIN>
__device__ __forceinline__ void node_mlp_body(
    const float* __restrict__ X, const float* __restrict__ W1,
    const float* __restrict__ b1, const unsigned short* __restrict__ W2Tn,
    const float* __restrict__ b2, float* __restrict__ out,
    float* __restrict__ cs, unsigned short* hbf, float* cspart, int r0) {
  int tid = threadIdx.x;
  int w = tid >> 6, l = tid & 63, l15 = l & 15, l4 = l >> 4;
  // ---- layer 1
  {
    float w1r[DIN];
#pragma unroll
    for (int d = 0; d < DIN; ++d) w1r[d] = W1[d * HH + tid];
    float b1h = b1[tid];
#pragma unroll
    for (int r = 0; r < 16; ++r) {
      const float* x = X + (size_t)(r0 + r) * DIN;
      float s = b1h;
#pragma unroll
      for (int d = 0; d < DIN; ++d) s += x[d] * w1r[d];
      hbf[r * 264 + tid] = f2bf(fmaxf(s, 0.f));
    }
  }
  __syncthreads();
  // ---- layer 2: wave w owns out cols [w*192, (w+1)*192) = 12 n-tiles
  bf8v a[8];
#pragma unroll
  for (int ks = 0; ks < 8; ++ks)
    a[ks] = *(const bf8v*)&hbf[l15 * 264 + ks * 32 + l4 * 8];
  float dsum[4][4];
#pragma unroll
  for (int q = 0; q < 4; ++q)
#pragma unroll
    for (int r = 0; r < 4; ++r) dsum[q][r] = 0.f;
#pragma unroll
  for (int nt = 0; nt < 12; ++nt) {
    int col = w * 192 + nt * 16 + l15;
    f4v c = (f4v){0.f, 0.f, 0.f, 0.f};
#pragma unroll
    for (int ks = 0; ks < 8; ++ks) {
      bf8v bfr = *(const bf8v*)&W2Tn[(size_t)col * 256 + ks * 32 + l4 * 8];
      c = __builtin_amdgcn_mfma_f32_16x16x32_bf16(a[ks], bfr, c, 0, 0, 0);
    }
    float bb = b2[col];
#pragma unroll
    for (int r = 0; r < 4; ++r) {
      float v = c[r] + bb;
      out[(size_t)(r0 + l4 * 4 + r) * 768 + col] = v;
      dsum[nt & 3][r] += v;
    }
  }
#pragma unroll
  for (int q = 0; q < 4; ++q)
#pragma unroll
    for (int r = 0; r < 4; ++r)
      cspart[(w * 16 + l4 * 4 + r) * 64 + q * 16 + l15] = dsum[q][r];
  __syncthreads();
#pragma unroll
  for (int rep = 0; rep < 4; ++rep) {
    int slot = tid + rep * 256;   // 0..1023
    int row = slot >> 6, d = slot & 63;
    cs[(size_t)(r0 + row) * DD + d] =
        cspart[(0 * 16 + row) * 64 + d] + cspart[(1 * 16 + row) * 64 + d] +
        cspart[(2 * 16 + row) * 64 + d] + cspart[(3 * 16 + row) * 64 + d];
  }
}

__global__ __launch_bounds__(256) void k_node_both(
    const float* __restrict__ attr_raw, const float* __restrict__ ptraits,
    const float* __restrict__ W1a, const float* __restrict__ b1a, const float* __restrict__ b2a,
    const float* __restrict__ W1b, const float* __restrict__ b1b, const float* __restrict__ b2b,
    const unsigned short* __restrict__ W2Tn,
    float* __restrict__ attr_img, float* __restrict__ cs_img,
    float* __restrict__ attr_user, float* __restrict__ cs_user) {
  __shared__ __align__(16) unsigned short hbf[16 * 264];   // 8448 B
  __shared__ __align__(16) float cspart[4 * 16 * 64];      // 16384 B
  int r0 = blockIdx.x * 16;
  if (blockIdx.y == 0)
    node_mlp_body<NATTR>(attr_raw, W1a, b1a, W2Tn, b2a, attr_img, cs_img, hbf, cspart, r0);
  else
    node_mlp_body<NPT>(ptraits, W1b, b1b, W2Tn + (size_t)768 * 256, b2b,
                       attr_user, cs_user, hbf, cspart, r0);
}

// ---------------------------------------------------------------- K4: internal interaction via MFMA (32x32)
// Packed Plds: only 144 real rows (p = j*12+i) + ONE shared zero row; pad lanes
// (i>=12) point their A-frag address at the zero row (same-addr broadcast = free).
// LDS 34.2K -> 27.2K => 5+ blocks/CU. Epilogue: relu(x+b)=max(x,-b)+b identity,
// corr = 12b - 4*relu(-b) folds pad contribution. Q stored bf16 (shQb, stride 264).
__global__ __launch_bounds__(256, 5) void k_internal_mfma(
    const float* __restrict__ attr_img, const float* __restrict__ attr_user,
    const unsigned short* __restrict__ W1T, const unsigned short* __restrict__ W2T,
    const float* __restrict__ b1i, const float* __restrict__ b1u,
    const float* __restrict__ b2i, const float* __restrict__ b2u,
    float* __restrict__ int_img, float* __restrict__ int_user) {
  int b = blockIdx.x, dt = blockIdx.y;
  const float* e_g = (dt ? attr_user : attr_img) + (size_t)b * (NATTR * DD);
  const float* b1 = dt ? b1u : b1i;
  const float* b2 = dt ? b2u : b2i;
  float* outp = (dt ? int_user : int_img) + (size_t)b * (NATTR * DD);

  __shared__ __align__(16) unsigned short shQb[12 * QST];      // 6336 B (bf16 Q)
  __shared__ __align__(16) unsigned short Plds[145 * 72];      // 20880 B (144 rows + zero row)
  float* elds = (float*)shQb;  // [12][68] f32 alias (3264 B); phases disjoint

  int tid = threadIdx.x, w = tid >> 6, l = tid & 63;
  int l15 = l & 15, l4 = l >> 4, l31 = l & 31, hi = l >> 5;

  // GEMM1 B-frags (32x32x16): wave w owns cols [w*64,(w+1)*64) = 2 N-tiles
  bf8v w1f[2][4];
#pragma unroll
  for (int nt = 0; nt < 2; ++nt)
#pragma unroll
    for (int ks = 0; ks < 4; ++ks)
      w1f[nt][ks] = *(const bf8v*)&W1T[(size_t)dt * 16384 +
                      (size_t)(w * 64 + nt * 32 + l31) * 64 + ks * 16 + hi * 8];
  // GEMM2 B-frags (16x16x32): wave w owns out cols d' in [w*16, w*16+16)
  bf8v w2f[8];
#pragma unroll
  for (int ks = 0; ks < 8; ++ks)
    w2f[ks] = *(const bf8v*)&W2T[(size_t)dt * 16384 +
                                 (size_t)(w * 16 + l15) * 256 + ks * 32 + l4 * 8];
  float b2v = b2[w * 16 + l15];
  float nb[2], corr[2];
#pragma unroll
  for (int nt = 0; nt < 2; ++nt) {
    float v = b1[w * 64 + nt * 32 + l31];
    nb[nt] = -v;
    corr[nt] = 12.f * v - 4.f * fmaxf(-v, 0.f);
  }

  // packed A-frag addressing: lane provides tile-row l31; i = l31&15, lh = l31>>4.
  // real row (i<12): packed row = (2m+lh)*12 + i -> base0 + m*step; pad: zero row.
  int i15 = l31 & 15, lh = l31 >> 4;
  int realrow = (i15 < NATTR);
  int abase = realrow ? (lh * 12 + i15) * 72 : ZROW;
  int astep = realrow ? (24 * 72) : 0;

  if (tid < 192) {
    int r = tid >> 4, c = tid & 15;
    *(float4*)&elds[r * 68 + c * 4] = ((const float4*)e_g)[tid];
  }
  if (tid < 36) ((unsigned int*)&Plds[ZROW])[tid] = 0u;   // shared zero row
  __syncthreads();

  // ---- stage P packed: 576 tasks = (row p=j*12+i, 16-elem quarter q4)
#pragma unroll
  for (int rep = 0; rep < 3; ++rep) {
    int t2 = tid + rep * 256;
    if (t2 < 576) {
      int p = t2 >> 2, q4 = t2 & 3;
      int j = p / NATTR, i = p - j * NATTR;
      unsigned int* dst = (unsigned int*)&Plds[p * 72 + q4 * 16];
      const float4* ei = (const float4*)(elds + i * 68 + q4 * 16);
      const float4* ej = (const float4*)(elds + j * 68 + q4 * 16);
      float4 a0 = ei[0], c0 = ej[0], a1 = ei[1], c1 = ej[1];
      float4 a2 = ei[2], c2 = ej[2], a3 = ei[3], c3 = ej[3];
      uint4 o0, o1;
      o0.x = pkbf(a0.x * c0.x, a0.y * c0.y); o0.y = pkbf(a0.z * c0.z, a0.w * c0.w);
      o0.z = pkbf(a1.x * c1.x, a1.y * c1.y); o0.w = pkbf(a1.z * c1.z, a1.w * c1.w);
      o1.x = pkbf(a2.x * c2.x, a2.y * c2.y); o1.y = pkbf(a2.z * c2.z, a2.w * c2.w);
      o1.z = pkbf(a3.x * c3.x, a3.y * c3.y); o1.w = pkbf(a3.z * c3.z, a3.w * c3.w);
      *(uint4*)dst = o0;
      *(uint4*)(dst + 4) = o1;
    }
  }
  __syncthreads();  // P staged; elds reads done (shQb writable from here)

  // ---- GEMM1 (32x32x16) + max(c,-b) tree-sum + segment-pair reduce into shQb
#pragma unroll
  for (int m = 0; m < 6; ++m) {
    bf8v a[4];
#pragma unroll
    for (int ks = 0; ks < 4; ++ks)
      a[ks] = *(const bf8v*)&Plds[abase + m * astep + ks * 16 + hi * 8];
#pragma unroll
    for (int nt = 0; nt < 2; ++nt) {
      f16v c = {0.f, 0.f, 0.f, 0.f, 0.f, 0.f, 0.f, 0.f,
                0.f, 0.f, 0.f, 0.f, 0.f, 0.f, 0.f, 0.f};
#pragma unroll
      for (int ks = 0; ks < 4; ++ks)
        c = __builtin_amdgcn_mfma_f32_32x32x16_bf16(a[ks], w1f[nt][ks], c, 0, 0, 0);
      float nbv = nb[nt];
      float sA = ((fmaxf(c[0], nbv) + fmaxf(c[1], nbv)) +
                  (fmaxf(c[2], nbv) + fmaxf(c[3], nbv))) +
                 ((fmaxf(c[4], nbv) + fmaxf(c[5], nbv)) +
                  (fmaxf(c[6], nbv) + fmaxf(c[7], nbv)));
      float sB = ((fmaxf(c[8], nbv) + fmaxf(c[9], nbv)) +
                  (fmaxf(c[10], nbv) + fmaxf(c[11], nbv))) +
                 ((fmaxf(c[12], nbv) + fmaxf(c[13], nbv)) +
                  (fmaxf(c[14], nbv) + fmaxf(c[15], nbv)));
      sA += __shfl_xor(sA, 32);
      sB += __shfl_xor(sB, 32);
      int col = w * 64 + nt * 32 + l31;
      if (hi == 0) shQb[(2 * m) * QST + col] = f2bf(sA + corr[nt]);
      else         shQb[(2 * m + 1) * QST + col] = f2bf(sB + corr[nt]);
    }
  }
  __syncthreads();

  // ---- GEMM2: out = Q@W2 + 12*b2 (Q already bf16 in LDS)
  f4v co = (f4v){0.f, 0.f, 0.f, 0.f};
#pragma unroll
  for (int ks = 0; ks < 8; ++ks) {
    bf8v aq;
    if (l15 < NATTR) {
      aq = *(const bf8v*)&shQb[l15 * QST + ks * 32 + l4 * 8];
    } else {
      aq = (bf8v){0, 0, 0, 0, 0, 0, 0, 0};
    }
    co = __builtin_amdgcn_mfma_f32_16x16x32_bf16(aq, w2f[ks], co, 0, 0, 0);
  }
#pragma unroll
  for (int r = 0; r < 4; ++r) {
    int j = l4 * 4 + r;
    if (j < NATTR) outp[j * DD + w * 16 + l15] = co[r] + 12.f * b2v;
  }
}

// ---------------------------------------------------------------- K5: GRU via MFMA (accumulates into out)
__global__ __launch_bounds__(256, 2) void k_gru_mfma(
    const float* __restrict__ attr_img, const float* __restrict__ attr_user,
    const float* __restrict__ int_img, const float* __restrict__ int_user,
    const float* __restrict__ cs_img, const float* __restrict__ cs_user,
    const unsigned short* __restrict__ WTg,
    const float* __restrict__ bih_i, const float* __restrict__ bhh_i,
    const float* __restrict__ bih_u, const float* __restrict__ bhh_u,
    const float* __restrict__ corr_W, float* __restrict__ out) {
  int blk = blockIdx.x, dt = blockIdx.y;
  int c0 = blk * 64;
  int tid = threadIdx.x, w = tid >> 6, l = tid & 63;
  int l15 = l & 15, l4 = l >> 4;

  const float* e   = (dt ? attr_user : attr_img);
  const float* itn = (dt ? int_user : int_img);
  const float* cs  = (dt ? cs_img : cs_user);   // cross: ext_img uses user colsum & v.v.
  const float* bih = (dt ? bih_u : bih_i);
  const float* bhh = (dt ? bhh_u : bhh_i);

  __shared__ __align__(16) unsigned short Wlds[2 * 192 * 72];
  __shared__ __align__(16) unsigned short Xb[64 * 72];
  __shared__ __align__(16) unsigned short Hb[64 * 72];

  {
    const unsigned short* src = WTg + (size_t)dt * (2 * 192 * 72);
    for (int v = tid; v < 3456; v += 256)
      *(bf8v*)&Wlds[v * 8] = *(const bf8v*)&src[v * 8];
  }
  // r/z gates use merged bih+bhh; n gate needs them separate.
  float bsum0[4], bsum1[4], bih2[4], bhh2[4], cw[4];
#pragma unroll
  for (int db = 0; db < 4; ++db) {
    int col = db * 16 + l15;
    bsum0[db] = bih[col] + bhh[col];
    bsum1[db] = bih[64 + col] + bhh[64 + col];
    bih2[db] = bih[128 + col];
    bhh2[db] = bhh[128 + col];
    cw[db] = corr_W[col];
  }

  float h_old[4][4];
#pragma unroll
  for (int db = 0; db < 4; ++db)
#pragma unroll
    for (int r = 0; r < 4; ++r) h_old[db][r] = 0.f;

  int row = tid >> 2;
  int chunk = tid & 3;
  size_t srcoff = (size_t)(c0 + row) * DD + chunk * 16;
  int bb_row = (c0 + row) / NATTR;

  __syncthreads();

#pragma unroll
  for (int step = 0; step < 3; ++step) {
    {
      const float* src = (step == 1 ? itn : e) + srcoff;
      float4 v0 = ((const float4*)src)[0];
      float4 v1 = ((const float4*)src)[1];
      float4 v2 = ((const float4*)src)[2];
      float4 v3 = ((const float4*)src)[3];
      if (step == 2) {
        const float4* c4 = (const float4*)(cs + (size_t)bb_row * DD + chunk * 16);
        float4 q0 = c4[0], q1 = c4[1], q2 = c4[2], q3 = c4[3];
        v0.x *= q0.x; v0.y *= q0.y; v0.z *= q0.z; v0.w *= q0.w;
        v1.x *= q1.x; v1.y *= q1.y; v1.z *= q1.z; v1.w *= q1.w;
        v2.x *= q2.x; v2.y *= q2.y; v2.z *= q2.z; v2.w *= q2.w;
        v3.x *= q3.x; v3.y *= q3.y; v3.z *= q3.z; v3.w *= q3.w;
      }
      uint4 o0, o1;
      o0.x = pkbf(v0.x, v0.y); o0.y = pkbf(v0.z, v0.w);
      o0.z = pkbf(v1.x, v1.y); o0.w = pkbf(v1.z, v1.w);
      o1.x = pkbf(v2.x, v2.y); o1.y = pkbf(v2.z, v2.w);
      o1.z = pkbf(v3.x, v3.y); o1.w = pkbf(v3.z, v3.w);
      unsigned int* dst = (unsigned int*)&Xb[row * 72 + chunk * 16];
      *(uint4*)dst = o0;
      *(uint4*)(dst + 4) = o1;
    }
    __syncthreads();

    f4v gi[3][4], gh[3][4];
#pragma unroll
    for (int t = 0; t < 3; ++t)
#pragma unroll
      for (int db = 0; db < 4; ++db) {
        gi[t][db] = (f4v){0.f, 0.f, 0.f, 0.f};
        gh[t][db] = (f4v){0.f, 0.f, 0.f, 0.f};
      }
#pragma unroll
    for (int ks = 0; ks < 2; ++ks) {
      bf8v ax = *(const bf8v*)&Xb[(w * 16 + l15) * 72 + ks * 32 + l4 * 8];
#pragma unroll
      for (int t = 0; t < 3; ++t)
#pragma unroll
        for (int db = 0; db < 4; ++db) {
          bf8v bw = *(const bf8v*)&Wlds[(t * 64 + db * 16 + l15) * 72 + ks * 32 + l4 * 8];
          gi[t][db] = __builtin_amdgcn_mfma_f32_16x16x32_bf16(ax, bw, gi[t][db], 0, 0, 0);
        }
      if (step > 0) {
        bf8v ah = *(const bf8v*)&Hb[(w * 16 + l15) * 72 + ks * 32 + l4 * 8];
#pragma unroll
        for (int t = 0; t < 3; ++t)
#pragma unroll
          for (int db = 0; db < 4; ++db) {
            bf8v bw = *(const bf8v*)&Wlds[(192 + t * 64 + db * 16 + l15) * 72 + ks * 32 + l4 * 8];
            gh[t][db] = __builtin_amdgcn_mfma_f32_16x16x32_bf16(ah, bw, gh[t][db], 0, 0, 0);
          }
      }
    }

#pragma unroll
    for (int db = 0; db < 4; ++db) {
#pragma unroll
      for (int r = 0; r < 4; ++r) {
        // r/z: sigmoid(gi+gh+(bih+bhh)); n: tanh((gi+bih) + r*(gh+bhh))
        float ar = gi[0][db][r] + gh[0][db][r] + bsum0[db];
        float az = gi[1][db][r] + gh[1][db][r] + bsum1[db];
        float in_ = gi[2][db][r] + bih2[db];
        float hn = gh[2][db][r] + bhh2[db];
        float rr = 1.f / (1.f + __expf(-ar));
        float zz = 1.f / (1.f + __expf(-az));
        float ax_ = in_ + rr * hn;
        ax_ = fminf(fmaxf(ax_, -15.f), 15.f);
        float e2 = __expf(-2.f * ax_);
        float nn = (1.f - e2) / (1.f + e2);
        float h = nn + zz * (h_old[db][r] - nn);   // == (1-z)n + z*h
        h_old[db][r] = h;
        if (step < 2)
          Hb[(w * 16 + l4 * 4 + r) * 72 + db * 16 + l15] = f2bf(h);
      }
    }
    __syncthreads();
  }

#pragma unroll
  for (int r = 0; r < 4; ++r) {
    float s = 0.f;
#pragma unroll
    for (int db = 0; db < 4; ++db) s += cw[db] * h_old[db][r];
#pragma unroll
    for (int m = 1; m < 16; m <<= 1) s += __shfl_xor(s, m);
    if (l15 == 0) {
      int chain = c0 + w * 16 + l4 * 4 + r;
      atomicAdd(&out[chain / NATTR], s);
    }
  }
}

// ---------------------------------------------------------------- launcher
extern "C" void kernel_launch(void* const* d_in, const int* in_sizes, int n_in,
                              void* d_out, int out_size, void* d_ws, size_t ws_size,
                              hipStream_t stream) {
  const float* images     = (const float*)d_in[0];
  const float* ptraits    = (const float*)d_in[1];
  const float* nima_Wl    = (const float*)d_in[2];
  const float* nima_bl    = (const float*)d_in[3];
  const float* nima_Wa    = (const float*)d_in[4];
  const float* nima_ba    = (const float*)d_in[5];
  const float* imgn_W1    = (const float*)d_in[6];
  const float* imgn_b1    = (const float*)d_in[7];
  const float* imgn_W2    = (const float*)d_in[8];
  const float* imgn_b2    = (const float*)d_in[9];
  const float* usrn_W1    = (const float*)d_in[10];
  const float* usrn_b1    = (const float*)d_in[11];
  const float* usrn_W2    = (const float*)d_in[12];
  const float* usrn_b2    = (const float*)d_in[13];
  const float* iiW1i      = (const float*)d_in[14];
  const float* iib1i      = (const float*)d_in[15];
  const float* iiW2i      = (const float*)d_in[16];
  const float* iib2i      = (const float*)d_in[17];
  const float* iiW1u      = (const float*)d_in[18];
  const float* iib1u      = (const float*)d_in[19];
  const float* iiW2u      = (const float*)d_in[20];
  const float* iib2u      = (const float*)d_in[21];
  const float* gWih_i     = (const float*)d_in[22];
  const float* gWhh_i     = (const float*)d_in[23];
  const float* gbih_i     = (const float*)d_in[24];
  const float* gbhh_i     = (const float*)d_in[25];
  const float* gWih_u     = (const float*)d_in[26];
  const float* gWhh_u     = (const float*)d_in[27];
  const float* gbih_u     = (const float*)d_in[28];
  const float* gbhh_u     = (const float*)d_in[29];
  const float* corr_W     = (const float*)d_in[30];
  const float* corr_b     = (const float*)d_in[31];
  const float* dist_W1    = (const float*)d_in[32];
  const float* dist_b1    = (const float*)d_in[33];
  const float* dist_W2    = (const float*)d_in[34];
  const float* dist_b2    = (const float*)d_in[35];

  float* ws = (float*)d_ws;
  float* WT        = ws;                       // 21*2048
  float* attr_raw  = WT + 21 * FEAT;           // B*12
  float* attr_img  = attr_raw + NB * NATTR;    // B*768
  float* attr_user = attr_img + NB * 768;      // B*768
  float* int_img   = attr_user + NB * 768;     // B*768
  float* int_user  = int_img + NB * 768;       // B*768
  float* cs_img    = int_user + NB * 768;      // B*64
  float* cs_user   = cs_img + NB * DD;         // B*64
  unsigned short* WTg  = (unsigned short*)(cs_user + NB * DD);  // 4*192*72
  unsigned short* W1T  = WTg + 4 * 192 * 72;              // 2*256*64
  unsigned short* W2T  = W1T + 2 * HH * DD;               // 2*64*256
  unsigned short* W2Tn = W2T + 2 * DD * HH;               // 2*768*256

  float* out = (float*)d_out;

  hipLaunchKernelGGL(k_prep_all, dim3(494), dim3(256), 0, stream,
                     nima_Wl, nima_Wa,
                     gWih_i, gWhh_i, gWih_u, gWhh_u,
                     iiW1i, iiW1u, iiW2i, iiW2u,
                     imgn_W2, usrn_W2,
                     WT, WTg, W1T, W2T, W2Tn);
  hipLaunchKernelGGL(k_nima, dim3(NB / 4), dim3(256), 0, stream,
                     images, WT, nima_bl, nima_ba,
                     dist_W1, dist_b1, dist_W2, dist_b2, corr_b,
                     attr_raw, out);
  hipLaunchKernelGGL(k_node_both, dim3(NB / 16, 2), dim3(256), 0, stream,
                     attr_raw, ptraits,
                     imgn_W1, imgn_b1, imgn_b2,
                     usrn_W1, usrn_b1, usrn_b2,
                     W2Tn,
                     attr_img, cs_img, attr_user, cs_user);
  hipLaunchKernelGGL(k_internal_mfma, dim3(NB, 2), dim3(256), 0, stream,
                     attr_img, attr_user, W1T, W2T,
                     iib1i, iib1u, iib2i, iib2u,
                     int_img, int_user);
  hipLaunchKernelGGL(k_gru_mfma, dim3(NB * NATTR / 64, 2), dim3(256), 0, stream,
                     attr_img, attr_user, int_img, int_user, cs_img, cs_user,
                     WTg, gbih_i, gbhh_i, gbih_u, gbhh_u, corr_W, out);
}

// Round 12
// 128.930 us; speedup vs baseline: 1.1215x; 1.1215x over previous
//
#include <hip/hip_runtime.h>
#include <hip/hip_bf16.h>

#define NB 2048      // batch
#define FEAT 2048
#define NBINS 9
#define NATTR 12
#define NPT 20
#define DD 64
#define HH 256
#define QST 272      // shQb row stride (shorts)

typedef __attribute__((ext_vector_type(8))) short bf8v;    // 8 bf16 (4 VGPRs) MFMA A/B frag
typedef __attribute__((ext_vector_type(4))) float f4v;     // 16x16 C/D frag
typedef __attribute__((ext_vector_type(16))) float f16v;   // 32x32 C/D frag

__device__ __forceinline__ unsigned short f2bf(float f) {
  unsigned int u = __float_as_uint(f);
  u += 0x7FFFu + ((u >> 16) & 1u);   // round-to-nearest-even
  return (unsigned short)(u >> 16);
}

// packed f32x2 -> bf16x2 (RNE — bit-identical to f2bf)
__device__ __forceinline__ unsigned int pkbf(float x, float y) {
  __hip_bfloat162 h = __float22bfloat162_rn(make_float2(x, y));
  union { __hip_bfloat162 h; unsigned int u; } cv;
  cv.h = h;
  return cv.u;
}

// ---------------------------------------------------------------- K0: merged weight prep
// bid<168: NIMA WT; [168,172): GRU WTg; [172,174): II W1T (K=64);
// [174,302): II W2T; [302,494): node W2Tn
__global__ void k_prep_all(
    const float* __restrict__ Wl, const float* __restrict__ Wa,
    const float* __restrict__ Wih_i, const float* __restrict__ Whh_i,
    const float* __restrict__ Wih_u, const float* __restrict__ Whh_u,
    const float* __restrict__ W1i, const float* __restrict__ W1u,
    const float* __restrict__ W2i, const float* __restrict__ W2u,
    const float* __restrict__ nW2i, const float* __restrict__ nW2u,
    float* __restrict__ WT, unsigned short* __restrict__ WTg,
    unsigned short* __restrict__ W1T, unsigned short* __restrict__ W2T,
    unsigned short* __restrict__ W2Tn) {
  int bid = blockIdx.x, tid = threadIdx.x;
  if (bid < 168) {
    int idx = bid * 256 + tid;
    if (idx < 21 * FEAT) {
      int c = idx / FEAT, k = idx - c * FEAT;
      WT[idx] = (c < NBINS) ? Wl[k * NBINS + c] : Wa[k * NATTR + (c - NBINS)];
    }
  } else if (bid < 172) {
    if (tid < 192) {
      int idx = bid - 168;
      const float* W = idx == 0 ? Wih_i : idx == 1 ? Whh_i : idx == 2 ? Wih_u : Whh_u;
      unsigned short* dst = WTg + (size_t)idx * 192 * 72 + (size_t)tid * 72;
      for (int k = 0; k < DD; ++k) dst[k] = f2bf(W[k * 192 + tid]);
    }
  } else if (bid < 174) {
    int dt = bid - 172;
    const float* W1 = dt ? W1u : W1i;
    unsigned short* dst = W1T + (size_t)dt * (HH * DD) + (size_t)tid * DD;
    for (int k = 0; k < DD; ++k) dst[k] = f2bf(W1[k * HH + tid]);
  } else if (bid < 302) {
    int t = (bid - 174) * 256 + tid;   // 0..32767
    int dt = t >> 14, rem = t & 16383;
    int dp = rem >> 8, k = rem & 255;
    W2T[t] = f2bf((dt ? W2u : W2i)[k * DD + dp]);
  } else {
    int idx8 = (bid - 302) * 256 + tid;   // 0..49151, 8 shorts each
    int dt = idx8 >= 24576;
    int rem = idx8 - dt * 24576;
    int o = rem >> 5, kb = (rem & 31) * 8;
    const float* W2n = dt ? nW2u : nW2i;   // [256][768]
    unsigned short* dst = W2Tn + (size_t)idx8 * 8;
#pragma unroll
    for (int e = 0; e < 8; ++e) dst[e] = f2bf(W2n[(size_t)(kb + e) * 768 + o]);
  }
}

// ---------------------------------------------------------------- K1: NIMA heads + direct path; writes out base
__global__ __launch_bounds__(256) void k_nima(
    const float* __restrict__ A, const float* __restrict__ WT,
    const float* __restrict__ bl, const float* __restrict__ ba,
    const float* __restrict__ dW1, const float* __restrict__ db1,
    const float* __restrict__ dW2, const float* __restrict__ db2,
    const float* __restrict__ corr_b,
    float* __restrict__ attr_raw, float* __restrict__ out) {
  int wave = threadIdx.x >> 6, lane = threadIdx.x & 63;
  int row = blockIdx.x * 4 + wave;
  const float4* A4 = (const float4*)(A + (size_t)row * FEAT);
  float acc[21];
#pragma unroll
  for (int c = 0; c < 21; ++c) acc[c] = 0.f;
#pragma unroll
  for (int it = 0; it < 8; ++it) {
    int kk = it * 64 + lane;
    float4 a = A4[kk];
#pragma unroll
    for (int c = 0; c < 21; ++c) {
      float4 w = ((const float4*)(WT + c * FEAT))[kk];
      acc[c] += a.x * w.x + a.y * w.y + a.z * w.z + a.w * w.w;
    }
  }
#pragma unroll
  for (int c = 0; c < 21; ++c) {
#pragma unroll
    for (int m = 1; m < 64; m <<= 1) acc[c] += __shfl_xor(acc[c], m);
  }
  if (lane == 0) {
#pragma unroll
    for (int c = 0; c < NATTR; ++c) attr_raw[row * NATTR + c] = acc[NBINS + c] + ba[c];
  }
  float l[NBINS];
  float mx = -1e30f;
#pragma unroll
  for (int i = 0; i < NBINS; ++i) { l[i] = acc[i] + bl[i]; mx = fmaxf(mx, l[i]); }
  float s = 0.f;
#pragma unroll
  for (int i = 0; i < NBINS; ++i) { l[i] = __expf(l[i] - mx); s += l[i]; }
  float inv = 1.f / s;
#pragma unroll
  for (int i = 0; i < NBINS; ++i) l[i] *= inv * (1.f + 0.5f * (float)i);
  float partial = 0.f;
#pragma unroll
  for (int hh = 0; hh < 4; ++hh) {
    int h = lane + hh * 64;
    float v = db1[h];
#pragma unroll
    for (int i = 0; i < NBINS; ++i) v += l[i] * dW1[i * HH + h];
    partial += fmaxf(v, 0.f) * dW2[h];
  }
#pragma unroll
  for (int m2 = 1; m2 < 64; m2 <<= 1) partial += __shfl_xor(partial, m2);
  // out base = direct + corr_b; k_gru atomically accumulates the interaction term.
  if (lane == 0) out[row] = partial + db2[0] + corr_b[0];
}

// ---------------------------------------------------------------- K3: node MLPs, layer2 via MFMA
template <int DIN>
__device__ __forceinline__ void node_mlp_body(
    const float* __restrict__ X, const float* __restrict__ W1,
    const float* __restrict__ b1, const unsigned short* __restrict__ W2Tn,
    const float* __restrict__ b2, float* __restrict__ out,
    float* __restrict__ cs, unsigned short* hbf, float* cspart, int r0) {
  int tid = threadIdx.x;
  int w = tid >> 6, l = tid & 63, l15 = l & 15, l4 = l >> 4;
  // ---- layer 1
  {
    float w1r[DIN];
#pragma unroll
    for (int d = 0; d < DIN; ++d) w1r[d] = W1[d * HH + tid];
    float b1h = b1[tid];
#pragma unroll
    for (int r = 0; r < 16; ++r) {
      const float* x = X + (size_t)(r0 + r) * DIN;
      float s = b1h;
#pragma unroll
      for (int d = 0; d < DIN; ++d) s += x[d] * w1r[d];
      hbf[r * 264 + tid] = f2bf(fmaxf(s, 0.f));
    }
  }
  __syncthreads();
  // ---- layer 2: wave w owns out cols [w*192, (w+1)*192) = 12 n-tiles
  bf8v a[8];
#pragma unroll
  for (int ks = 0; ks < 8; ++ks)
    a[ks] = *(const bf8v*)&hbf[l15 * 264 + ks * 32 + l4 * 8];
  float dsum[4][4];
#pragma unroll
  for (int q = 0; q < 4; ++q)
#pragma unroll
    for (int r = 0; r < 4; ++r) dsum[q][r] = 0.f;
#pragma unroll
  for (int nt = 0; nt < 12; ++nt) {
    int col = w * 192 + nt * 16 + l15;
    f4v c = (f4v){0.f, 0.f, 0.f, 0.f};
#pragma unroll
    for (int ks = 0; ks < 8; ++ks) {
      bf8v bfr = *(const bf8v*)&W2Tn[(size_t)col * 256 + ks * 32 + l4 * 8];
      c = __builtin_amdgcn_mfma_f32_16x16x32_bf16(a[ks], bfr, c, 0, 0, 0);
    }
    float bb = b2[col];
#pragma unroll
    for (int r = 0; r < 4; ++r) {
      float v = c[r] + bb;
      out[(size_t)(r0 + l4 * 4 + r) * 768 + col] = v;
      dsum[nt & 3][r] += v;
    }
  }
#pragma unroll
  for (int q = 0; q < 4; ++q)
#pragma unroll
    for (int r = 0; r < 4; ++r)
      cspart[(w * 16 + l4 * 4 + r) * 64 + q * 16 + l15] = dsum[q][r];
  __syncthreads();
#pragma unroll
  for (int rep = 0; rep < 4; ++rep) {
    int slot = tid + rep * 256;   // 0..1023
    int row = slot >> 6, d = slot & 63;
    cs[(size_t)(r0 + row) * DD + d] =
        cspart[(0 * 16 + row) * 64 + d] + cspart[(1 * 16 + row) * 64 + d] +
        cspart[(2 * 16 + row) * 64 + d] + cspart[(3 * 16 + row) * 64 + d];
  }
}

__global__ __launch_bounds__(256) void k_node_both(
    const float* __restrict__ attr_raw, const float* __restrict__ ptraits,
    const float* __restrict__ W1a, const float* __restrict__ b1a, const float* __restrict__ b2a,
    const float* __restrict__ W1b, const float* __restrict__ b1b, const float* __restrict__ b2b,
    const unsigned short* __restrict__ W2Tn,
    float* __restrict__ attr_img, float* __restrict__ cs_img,
    float* __restrict__ attr_user, float* __restrict__ cs_user) {
  __shared__ __align__(16) unsigned short hbf[16 * 264];   // 8448 B
  __shared__ __align__(16) float cspart[4 * 16 * 64];      // 16384 B
  int r0 = blockIdx.x * 16;
  if (blockIdx.y == 0)
    node_mlp_body<NATTR>(attr_raw, W1a, b1a, W2Tn, b2a, attr_img, cs_img, hbf, cspart, r0);
  else
    node_mlp_body<NPT>(ptraits, W1b, b1b, W2Tn + (size_t)768 * 256, b2b,
                       attr_user, cs_user, hbf, cspart, r0);
}

// ---------------------------------------------------------------- K4: internal interaction via MFMA (32x32)
// R10-proven config (best known: 48.2us, 0 conflicts). relu(x+b)=max(x,-b)+b identity:
// epilogue = fmax(c,nb) tree-sum; pad rows contribute exactly 4*max(0,-b) per segment
// (hi=1 lanes) -> folded into corr = 12b - 4*relu(-b). Q stored bf16 (shQb).
__global__ __launch_bounds__(256, 4) void k_internal_mfma(
    const float* __restrict__ attr_img, const float* __restrict__ attr_user,
    const unsigned short* __restrict__ W1T, const unsigned short* __restrict__ W2T,
    const float* __restrict__ b1i, const float* __restrict__ b1u,
    const float* __restrict__ b2i, const float* __restrict__ b2u,
    float* __restrict__ int_img, float* __restrict__ int_user) {
  int b = blockIdx.x, dt = blockIdx.y;
  const float* e_g = (dt ? attr_user : attr_img) + (size_t)b * (NATTR * DD);
  const float* b1 = dt ? b1u : b1i;
  const float* b2 = dt ? b2u : b2i;
  float* outp = (dt ? int_user : int_img) + (size_t)b * (NATTR * DD);

  __shared__ __align__(16) unsigned short shQb[12 * QST];    // 6528 B (bf16 Q)
  __shared__ __align__(16) unsigned short Plds[192 * 72];    // 27648 B
  float* elds = (float*)shQb;  // [12][68] f32 alias (3264 B); phases disjoint

  int tid = threadIdx.x, w = tid >> 6, l = tid & 63;
  int l15 = l & 15, l4 = l >> 4, l31 = l & 31, hi = l >> 5;

  // GEMM1 B-frags (32x32x16): wave w owns cols [w*64,(w+1)*64) = 2 N-tiles
  bf8v w1f[2][4];
#pragma unroll
  for (int nt = 0; nt < 2; ++nt)
#pragma unroll
    for (int ks = 0; ks < 4; ++ks)
      w1f[nt][ks] = *(const bf8v*)&W1T[(size_t)dt * 16384 +
                      (size_t)(w * 64 + nt * 32 + l31) * 64 + ks * 16 + hi * 8];
  // GEMM2 B-frags (16x16x32): wave w owns out cols d' in [w*16, w*16+16)
  bf8v w2f[8];
#pragma unroll
  for (int ks = 0; ks < 8; ++ks)
    w2f[ks] = *(const bf8v*)&W2T[(size_t)dt * 16384 +
                                 (size_t)(w * 16 + l15) * 256 + ks * 32 + l4 * 8];
  float b2v = b2[w * 16 + l15];
  float nb[2], corr[2];
#pragma unroll
  for (int nt = 0; nt < 2; ++nt) {
    float v = b1[w * 64 + nt * 32 + l31];
    nb[nt] = -v;
    corr[nt] = 12.f * v - 4.f * fmaxf(-v, 0.f);
  }

  if (tid < 192) {
    int r = tid >> 4, c = tid & 15;
    *(float4*)&elds[r * 68 + c * 4] = ((const float4*)e_g)[tid];
  }
  __syncthreads();

  // ---- stage P': 768 tasks = (row p=j*16+i, 16-elem quarter q4), 3/thread
#pragma unroll
  for (int rep = 0; rep < 3; ++rep) {
    int t2 = tid + rep * 256;
    int p = t2 >> 2, q4 = t2 & 3;
    int j = p >> 4, i = p & 15;
    unsigned int* dst = (unsigned int*)&Plds[p * 72 + q4 * 16];
    if (i < NATTR) {
      const float4* ei = (const float4*)(elds + i * 68 + q4 * 16);
      const float4* ej = (const float4*)(elds + j * 68 + q4 * 16);
      float4 a0 = ei[0], c0 = ej[0], a1 = ei[1], c1 = ej[1];
      float4 a2 = ei[2], c2 = ej[2], a3 = ei[3], c3 = ej[3];
      uint4 o0, o1;
      o0.x = pkbf(a0.x * c0.x, a0.y * c0.y); o0.y = pkbf(a0.z * c0.z, a0.w * c0.w);
      o0.z = pkbf(a1.x * c1.x, a1.y * c1.y); o0.w = pkbf(a1.z * c1.z, a1.w * c1.w);
      o1.x = pkbf(a2.x * c2.x, a2.y * c2.y); o1.y = pkbf(a2.z * c2.z, a2.w * c2.w);
      o1.z = pkbf(a3.x * c3.x, a3.y * c3.y); o1.w = pkbf(a3.z * c3.z, a3.w * c3.w);
      *(uint4*)dst = o0;
      *(uint4*)(dst + 4) = o1;
    } else {
      uint4 z = {0u, 0u, 0u, 0u};
      *(uint4*)dst = z;
      *(uint4*)(dst + 4) = z;
    }
  }
  __syncthreads();  // P' staged; elds reads done (shQb writable from here)

  // ---- GEMM1 (32x32x16) + max(c,-b) tree-sum + segment-pair reduce into shQb
#pragma unroll
  for (int m = 0; m < 6; ++m) {
    bf8v a[4];
#pragma unroll
    for (int ks = 0; ks < 4; ++ks)
      a[ks] = *(const bf8v*)&Plds[(m * 32 + l31) * 72 + ks * 16 + hi * 8];
#pragma unroll
    for (int nt = 0; nt < 2; ++nt) {
      f16v c = {0.f, 0.f, 0.f, 0.f, 0.f, 0.f, 0.f, 0.f,
                0.f, 0.f, 0.f, 0.f, 0.f, 0.f, 0.f, 0.f};
#pragma unroll
      for (int ks = 0; ks < 4; ++ks)
        c = __builtin_amdgcn_mfma_f32_32x32x16_bf16(a[ks], w1f[nt][ks], c, 0, 0, 0);
      float nbv = nb[nt];
      float sA = ((fmaxf(c[0], nbv) + fmaxf(c[1], nbv)) +
                  (fmaxf(c[2], nbv) + fmaxf(c[3], nbv))) +
                 ((fmaxf(c[4], nbv) + fmaxf(c[5], nbv)) +
                  (fmaxf(c[6], nbv) + fmaxf(c[7], nbv)));
      float sB = ((fmaxf(c[8], nbv) + fmaxf(c[9], nbv)) +
                  (fmaxf(c[10], nbv) + fmaxf(c[11], nbv))) +
                 ((fmaxf(c[12], nbv) + fmaxf(c[13], nbv)) +
                  (fmaxf(c[14], nbv) + fmaxf(c[15], nbv)));
      sA += __shfl_xor(sA, 32);
      sB += __shfl_xor(sB, 32);
      int col = w * 64 + nt * 32 + l31;
      if (hi == 0) shQb[(2 * m) * QST + col] = f2bf(sA + corr[nt]);
      else         shQb[(2 * m + 1) * QST + col] = f2bf(sB + corr[nt]);
    }
  }
  __syncthreads();

  // ---- GEMM2: out = Q@W2 + 12*b2 (Q already bf16 in LDS)
  f4v co = (f4v){0.f, 0.f, 0.f, 0.f};
#pragma unroll
  for (int ks = 0; ks < 8; ++ks) {
    bf8v aq;
    if (l15 < NATTR) {
      aq = *(const bf8v*)&shQb[l15 * QST + ks * 32 + l4 * 8];
    } else {
      aq = (bf8v){0, 0, 0, 0, 0, 0, 0, 0};
    }
    co = __builtin_amdgcn_mfma_f32_16x16x32_bf16(aq, w2f[ks], co, 0, 0, 0);
  }
#pragma unroll
  for (int r = 0; r < 4; ++r) {
    int j = l4 * 4 + r;
    if (j < NATTR) outp[j * DD + w * 16 + l15] = co[r] + 12.f * b2v;
  }
}

// ---------------------------------------------------------------- K5: GRU via MFMA (accumulates into out)
// r/z gates: x@Wih and h@Whh chained into the SAME MFMA accumulator (C in/out);
// only the n gate keeps gi/gh separate (r multiplies hn). 24 -> 16 f4v accumulators.
__global__ __launch_bounds__(256, 2) void k_gru_mfma(
    const float* __restrict__ attr_img, const float* __restrict__ attr_user,
    const float* __restrict__ int_img, const float* __restrict__ int_user,
    const float* __restrict__ cs_img, const float* __restrict__ cs_user,
    const unsigned short* __restrict__ WTg,
    const float* __restrict__ bih_i, const float* __restrict__ bhh_i,
    const float* __restrict__ bih_u, const float* __restrict__ bhh_u,
    const float* __restrict__ corr_W, float* __restrict__ out) {
  int blk = blockIdx.x, dt = blockIdx.y;
  int c0 = blk * 64;
  int tid = threadIdx.x, w = tid >> 6, l = tid & 63;
  int l15 = l & 15, l4 = l >> 4;

  const float* e   = (dt ? attr_user : attr_img);
  const float* itn = (dt ? int_user : int_img);
  const float* cs  = (dt ? cs_img : cs_user);   // cross: ext_img uses user colsum & v.v.
  const float* bih = (dt ? bih_u : bih_i);
  const float* bhh = (dt ? bhh_u : bhh_i);

  __shared__ __align__(16) unsigned short Wlds[2 * 192 * 72];
  __shared__ __align__(16) unsigned short Xb[64 * 72];
  __shared__ __align__(16) unsigned short Hb[64 * 72];

  {
    const unsigned short* src = WTg + (size_t)dt * (2 * 192 * 72);
    for (int v = tid; v < 3456; v += 256)
      *(bf8v*)&Wlds[v * 8] = *(const bf8v*)&src[v * 8];
  }
  // r/z gates use merged bih+bhh; n gate needs them separate.
  float bsum0[4], bsum1[4], bih2[4], bhh2[4], cw[4];
#pragma unroll
  for (int db = 0; db < 4; ++db) {
    int col = db * 16 + l15;
    bsum0[db] = bih[col] + bhh[col];
    bsum1[db] = bih[64 + col] + bhh[64 + col];
    bih2[db] = bih[128 + col];
    bhh2[db] = bhh[128 + col];
    cw[db] = corr_W[col];
  }

  float h_old[4][4];
#pragma unroll
  for (int db = 0; db < 4; ++db)
#pragma unroll
    for (int r = 0; r < 4; ++r) h_old[db][r] = 0.f;

  int row = tid >> 2;
  int chunk = tid & 3;
  size_t srcoff = (size_t)(c0 + row) * DD + chunk * 16;
  int bb_row = (c0 + row) / NATTR;

  __syncthreads();

#pragma unroll
  for (int step = 0; step < 3; ++step) {
    {
      const float* src = (step == 1 ? itn : e) + srcoff;
      float4 v0 = ((const float4*)src)[0];
      float4 v1 = ((const float4*)src)[1];
      float4 v2 = ((const float4*)src)[2];
      float4 v3 = ((const float4*)src)[3];
      if (step == 2) {
        const float4* c4 = (const float4*)(cs + (size_t)bb_row * DD + chunk * 16);
        float4 q0 = c4[0], q1 = c4[1], q2 = c4[2], q3 = c4[3];
        v0.x *= q0.x; v0.y *= q0.y; v0.z *= q0.z; v0.w *= q0.w;
        v1.x *= q1.x; v1.y *= q1.y; v1.z *= q1.z; v1.w *= q1.w;
        v2.x *= q2.x; v2.y *= q2.y; v2.z *= q2.z; v2.w *= q2.w;
        v3.x *= q3.x; v3.y *= q3.y; v3.z *= q3.z; v3.w *= q3.w;
      }
      uint4 o0, o1;
      o0.x = pkbf(v0.x, v0.y); o0.y = pkbf(v0.z, v0.w);
      o0.z = pkbf(v1.x, v1.y); o0.w = pkbf(v1.z, v1.w);
      o1.x = pkbf(v2.x, v2.y); o1.y = pkbf(v2.z, v2.w);
      o1.z = pkbf(v3.x, v3.y); o1.w = pkbf(v3.z, v3.w);
      unsigned int* dst = (unsigned int*)&Xb[row * 72 + chunk * 16];
      *(uint4*)dst = o0;
      *(uint4*)(dst + 4) = o1;
    }
    __syncthreads();

    f4v accr[4], accz[4], gin[4], ghn[4];
#pragma unroll
    for (int db = 0; db < 4; ++db) {
      accr[db] = (f4v){0.f, 0.f, 0.f, 0.f};
      accz[db] = (f4v){0.f, 0.f, 0.f, 0.f};
      gin[db]  = (f4v){0.f, 0.f, 0.f, 0.f};
      ghn[db]  = (f4v){0.f, 0.f, 0.f, 0.f};
    }
#pragma unroll
    for (int ks = 0; ks < 2; ++ks) {
      bf8v ax = *(const bf8v*)&Xb[(w * 16 + l15) * 72 + ks * 32 + l4 * 8];
#pragma unroll
      for (int db = 0; db < 4; ++db) {
        bf8v bw0 = *(const bf8v*)&Wlds[(0 * 64 + db * 16 + l15) * 72 + ks * 32 + l4 * 8];
        accr[db] = __builtin_amdgcn_mfma_f32_16x16x32_bf16(ax, bw0, accr[db], 0, 0, 0);
        bf8v bw1 = *(const bf8v*)&Wlds[(1 * 64 + db * 16 + l15) * 72 + ks * 32 + l4 * 8];
        accz[db] = __builtin_amdgcn_mfma_f32_16x16x32_bf16(ax, bw1, accz[db], 0, 0, 0);
        bf8v bw2 = *(const bf8v*)&Wlds[(2 * 64 + db * 16 + l15) * 72 + ks * 32 + l4 * 8];
        gin[db] = __builtin_amdgcn_mfma_f32_16x16x32_bf16(ax, bw2, gin[db], 0, 0, 0);
      }
      if (step > 0) {
        bf8v ah = *(const bf8v*)&Hb[(w * 16 + l15) * 72 + ks * 32 + l4 * 8];
#pragma unroll
        for (int db = 0; db < 4; ++db) {
          bf8v bw0 = *(const bf8v*)&Wlds[(192 + 0 * 64 + db * 16 + l15) * 72 + ks * 32 + l4 * 8];
          accr[db] = __builtin_amdgcn_mfma_f32_16x16x32_bf16(ah, bw0, accr[db], 0, 0, 0);
          bf8v bw1 = *(const bf8v*)&Wlds[(192 + 1 * 64 + db * 16 + l15) * 72 + ks * 32 + l4 * 8];
          accz[db] = __builtin_amdgcn_mfma_f32_16x16x32_bf16(ah, bw1, accz[db], 0, 0, 0);
          bf8v bw2 = *(const bf8v*)&Wlds[(192 + 2 * 64 + db * 16 + l15) * 72 + ks * 32 + l4 * 8];
          ghn[db] = __builtin_amdgcn_mfma_f32_16x16x32_bf16(ah, bw2, ghn[db], 0, 0, 0);
        }
      }
    }

#pragma unroll
    for (int db = 0; db < 4; ++db) {
#pragma unroll
      for (int r = 0; r < 4; ++r) {
        // r/z: sigmoid(acc + (bih+bhh)); n: tanh((gi+bih) + r*(gh+bhh))
        float ar = accr[db][r] + bsum0[db];
        float az = accz[db][r] + bsum1[db];
        float in_ = gin[db][r] + bih2[db];
        float hn = ghn[db][r] + bhh2[db];
        float rr = 1.f / (1.f + __expf(-ar));
        float zz = 1.f / (1.f + __expf(-az));
        float ax_ = in_ + rr * hn;
        ax_ = fminf(fmaxf(ax_, -15.f), 15.f);
        float e2 = __expf(-2.f * ax_);
        float nn = (1.f - e2) / (1.f + e2);
        float h = nn + zz * (h_old[db][r] - nn);   // == (1-z)n + z*h
        h_old[db][r] = h;
        if (step < 2)
          Hb[(w * 16 + l4 * 4 + r) * 72 + db * 16 + l15] = f2bf(h);
      }
    }
    __syncthreads();
  }

#pragma unroll
  for (int r = 0; r < 4; ++r) {
    float s = 0.f;
#pragma unroll
    for (int db = 0; db < 4; ++db) s += cw[db] * h_old[db][r];
#pragma unroll
    for (int m = 1; m < 16; m <<= 1) s += __shfl_xor(s, m);
    if (l15 == 0) {
      int chain = c0 + w * 16 + l4 * 4 + r;
      atomicAdd(&out[chain / NATTR], s);
    }
  }
}

// ---------------------------------------------------------------- launcher
extern "C" void kernel_launch(void* const* d_in, const int* in_sizes, int n_in,
                              void* d_out, int out_size, void* d_ws, size_t ws_size,
                              hipStream_t stream) {
  const float* images     = (const float*)d_in[0];
  const float* ptraits    = (const float*)d_in[1];
  const float* nima_Wl    = (const float*)d_in[2];
  const float* nima_bl    = (const float*)d_in[3];
  const float* nima_Wa    = (const float*)d_in[4];
  const float* nima_ba    = (const float*)d_in[5];
  const float* imgn_W1    = (const float*)d_in[6];
  const float* imgn_b1    = (const float*)d_in[7];
  const float* imgn_W2    = (const float*)d_in[8];
  const float* imgn_b2    = (const float*)d_in[9];
  const float* usrn_W1    = (const float*)d_in[10];
  const float* usrn_b1    = (const float*)d_in[11];
  const float* usrn_W2    = (const float*)d_in[12];
  const float* usrn_b2    = (const float*)d_in[13];
  const float* iiW1i      = (const float*)d_in[14];
  const float* iib1i      = (const float*)d_in[15];
  const float* iiW2i      = (const float*)d_in[16];
  const float* iib2i      = (const float*)d_in[17];
  const float* iiW1u      = (const float*)d_in[18];
  const float* iib1u      = (const float*)d_in[19];
  const float* iiW2u      = (const float*)d_in[20];
  const float* iib2u      = (const float*)d_in[21];
  const float* gWih_i     = (const float*)d_in[22];
  const float* gWhh_i     = (const float*)d_in[23];
  const float* gbih_i     = (const float*)d_in[24];
  const float* gbhh_i     = (const float*)d_in[25];
  const float* gWih_u     = (const float*)d_in[26];
  const float* gWhh_u     = (const float*)d_in[27];
  const float* gbih_u     = (const float*)d_in[28];
  const float* gbhh_u     = (const float*)d_in[29];
  const float* corr_W     = (const float*)d_in[30];
  const float* corr_b     = (const float*)d_in[31];
  const float* dist_W1    = (const float*)d_in[32];
  const float* dist_b1    = (const float*)d_in[33];
  const float* dist_W2    = (const float*)d_in[34];
  const float* dist_b2    = (const float*)d_in[35];

  float* ws = (float*)d_ws;
  float* WT        = ws;                       // 21*2048
  float* attr_raw  = WT + 21 * FEAT;           // B*12
  float* attr_img  = attr_raw + NB * NATTR;    // B*768
  float* attr_user = attr_img + NB * 768;      // B*768
  float* int_img   = attr_user + NB * 768;     // B*768
  float* int_user  = int_img + NB * 768;       // B*768
  float* cs_img    = int_user + NB * 768;      // B*64
  float* cs_user   = cs_img + NB * DD;         // B*64
  unsigned short* WTg  = (unsigned short*)(cs_user + NB * DD);  // 4*192*72
  unsigned short* W1T  = WTg + 4 * 192 * 72;              // 2*256*64
  unsigned short* W2T  = W1T + 2 * HH * DD;               // 2*64*256
  unsigned short* W2Tn = W2T + 2 * DD * HH;               // 2*768*256

  float* out = (float*)d_out;

  hipLaunchKernelGGL(k_prep_all, dim3(494), dim3(256), 0, stream,
                     nima_Wl, nima_Wa,
                     gWih_i, gWhh_i, gWih_u, gWhh_u,
                     iiW1i, iiW1u, iiW2i, iiW2u,
                     imgn_W2, usrn_W2,
                     WT, WTg, W1T, W2T, W2Tn);
  hipLaunchKernelGGL(k_nima, dim3(NB / 4), dim3(256), 0, stream,
                     images, WT, nima_bl, nima_ba,
                     dist_W1, dist_b1, dist_W2, dist_b2, corr_b,
                     attr_raw, out);
  hipLaunchKernelGGL(k_node_both, dim3(NB / 16, 2), dim3(256), 0, stream,
                     attr_raw, ptraits,
                     imgn_W1, imgn_b1, imgn_b2,
                     usrn_W1, usrn_b1, usrn_b2,
                     W2Tn,
                     attr_img, cs_img, attr_user, cs_user);
  hipLaunchKernelGGL(k_internal_mfma, dim3(NB, 2), dim3(256), 0, stream,
                     attr_img, attr_user, W1T, W2T,
                     iib1i, iib1u, iib2i, iib2u,
                     int_img, int_user);
  hipLaunchKernelGGL(k_gru_mfma, dim3(NB * NATTR / 64, 2), dim3(256), 0, stream,
                     attr_img, attr_user, int_img, int_user, cs_img, cs_user,
                     WTg, gbih_i, gbhh_i, gbih_u, gbhh_u, corr_W, out);
}